// Round 1
// baseline (543.769 us; speedup 1.0000x reference)
//
#include <hip/hip_runtime.h>
#include <math.h>

// ---------------------------------------------------------------------------
// Mamba3DBlock forward, fp32, correctness-first round.
// B=4, Npts=2048, C=384, K_GROUP=8. x rows = 4*2049 = 8196.
// ---------------------------------------------------------------------------

#define C384 384

__device__ __forceinline__ float gelu_exact(float v) {
    // jax.nn.gelu(approximate=False) = 0.5*x*(1+erf(x/sqrt(2)))
    return 0.5f * v * (1.0f + erff(v * 0.7071067811865475f));
}

// ---------------- LayerNorm over last dim (C=384), one block per row --------
__global__ __launch_bounds__(128) void ln_kernel(const float* __restrict__ in,
                                                 float* __restrict__ outp,
                                                 const float* __restrict__ g,
                                                 const float* __restrict__ b) {
    int row = blockIdx.x;
    int t = threadIdx.x;
    const float* x = in + (size_t)row * C384;
    float v0 = x[t], v1 = x[t + 128], v2 = x[t + 256];
    __shared__ float red[128];
    red[t] = v0 + v1 + v2;
    __syncthreads();
#pragma unroll
    for (int s = 64; s; s >>= 1) {
        if (t < s) red[t] += red[t + s];
        __syncthreads();
    }
    float m = red[0] / 384.0f;
    __syncthreads();
    float d0 = v0 - m, d1 = v1 - m, d2v = v2 - m;
    red[t] = d0 * d0 + d1 * d1 + d2v * d2v;
    __syncthreads();
#pragma unroll
    for (int s = 64; s; s >>= 1) {
        if (t < s) red[t] += red[t + s];
        __syncthreads();
    }
    float var = red[0] / 384.0f;
    float rstd = 1.0f / sqrtf(var + 1e-5f);
    float* o = outp + (size_t)row * C384;
    o[t]       = d0  * rstd * g[t]       + b[t];
    o[t + 128] = d1  * rstd * g[t + 128] + b[t + 128];
    o[t + 256] = d2v * rstd * g[t + 256] + b[t + 256];
}

// ---------------- KNN: top-8 smallest d2, tie -> lower index ----------------
// One block (256 threads) per query point. 2048 candidates, 8 per thread.
__global__ __launch_bounds__(256) void knn_kernel(const float* __restrict__ center,
                                                  int* __restrict__ idx_out) {
    int q = blockIdx.x;            // 0..8191  (b*2048 + n)
    int b = q >> 11, n = q & 2047;
    const float* cb = center + (size_t)b * 2048 * 3;
    float qx = cb[n * 3], qy = cb[n * 3 + 1], qz = cb[n * 3 + 2];
    float sqq = qx * qx + qy * qy + qz * qz;
    int t = threadIdx.x;
    unsigned long long key[8];
#pragma unroll
    for (int i = 0; i < 8; ++i) {
        int m = t + i * 256;
        float cx = cb[m * 3], cy = cb[m * 3 + 1], cz = cb[m * 3 + 2];
        float sqm = cx * cx + cy * cy + cz * cz;
        float dot = qx * cx + qy * cy + qz * cz;
        float d2 = (sqq + sqm) - 2.0f * dot;
        unsigned u = __float_as_uint(d2);
        u = (u & 0x80000000u) ? ~u : (u | 0x80000000u);  // order-preserving map
        key[i] = ((unsigned long long)u << 32) | (unsigned)m;
    }
    __shared__ unsigned long long red[256];
    for (int sel = 0; sel < 8; ++sel) {
        unsigned long long best = key[0];
#pragma unroll
        for (int i = 1; i < 8; ++i) best = (key[i] < best) ? key[i] : best;
        red[t] = best;
        __syncthreads();
#pragma unroll
        for (int s = 128; s; s >>= 1) {
            if (t < s) {
                unsigned long long o = red[t + s];
                if (o < red[t]) red[t] = o;
            }
            __syncthreads();
        }
        unsigned long long win = red[0];
        __syncthreads();
        if (t == 0) idx_out[(size_t)q * 8 + sel] = (int)(win & 0xffffffffu);
#pragma unroll
        for (int i = 0; i < 8; ++i)
            if (key[i] == win) key[i] = ~0ULL;
    }
}

// ---------------- gather 8 neighbors: sum_k x_no[idx_k][c], std partials ----
__global__ __launch_bounds__(128) void gather_kernel(const float* __restrict__ xn,
                                                     const int* __restrict__ idxb,
                                                     float* __restrict__ sumknn,
                                                     float2* __restrict__ part) {
    int q = blockIdx.x;   // b*2048 + n
    int b = q >> 11;
    int t = threadIdx.x;
    __shared__ int sidx[8];
    if (t < 8) sidx[t] = idxb[(size_t)q * 8 + t];
    __syncthreads();
    const float* xno = xn + ((size_t)b * 2049 + 1) * C384;   // x_no base of batch
    const float* xc  = xn + ((size_t)q + b + 1) * C384;      // row b*2049+1+n
    float s1 = 0.f, s2 = 0.f;
    for (int c = t; c < C384; c += 128) {
        float xcv = xc[c];
        float acc = 0.f;
#pragma unroll
        for (int k = 0; k < 8; ++k) {
            float v = xno[(size_t)sidx[k] * C384 + c];
            acc += v;
            float d = v - xcv;
            s1 += d;
            s2 += d * d;
        }
        sumknn[(size_t)q * C384 + c] = acc;
    }
    __shared__ float r1[128], r2[128];
    r1[t] = s1; r2[t] = s2;
    __syncthreads();
#pragma unroll
    for (int s = 64; s; s >>= 1) {
        if (t < s) { r1[t] += r1[t + s]; r2[t] += r2[t + s]; }
        __syncthreads();
    }
    if (t == 0) part[q] = make_float2(r1[0], r2[0]);
}

// ---------------- reduce std partials -> inv = 1/(std+1e-5) -----------------
__global__ __launch_bounds__(256) void std_kernel(const float2* __restrict__ part,
                                                  float* __restrict__ stdbuf) {
    int t = threadIdx.x;
    double s1 = 0.0, s2 = 0.0;
    for (int i = t; i < 8192; i += 256) {
        float2 p = part[i];
        s1 += (double)p.x;
        s2 += (double)p.y;
    }
    __shared__ double r1[256], r2[256];
    r1[t] = s1; r2[t] = s2;
    __syncthreads();
#pragma unroll
    for (int s = 128; s; s >>= 1) {
        if (t < s) { r1[t] += r1[t + s]; r2[t] += r2[t + s]; }
        __syncthreads();
    }
    if (t == 0) {
        const double N = 25165824.0;  // 4*2048*8*384
        double var = (r2[0] - r1[0] * r1[0] / N) / (N - 1.0);
        float stdf = (float)sqrt(var);
        stdbuf[0] = 1.0f / (stdf + 1e-5f);
    }
}

// ---------------- build ef (8192 x 768) --------------------------------------
__global__ __launch_bounds__(384) void ef_kernel(const float* __restrict__ xn,
                                                 const float* __restrict__ sumknn,
                                                 const float* __restrict__ stdbuf,
                                                 const float* __restrict__ alpha,
                                                 const float* __restrict__ beta,
                                                 float* __restrict__ ef) {
    int q = blockIdx.x;  // b*2048+n
    int b = q >> 11;
    int c = threadIdx.x;
    float inv = stdbuf[0];
    float xcv = xn[((size_t)q + b + 1) * C384 + c];
    float mk = sumknn[(size_t)q * C384 + c] * 0.125f;
    float v1 = (mk - xcv) * inv;
    ef[(size_t)q * 768 + c]       = alpha[c] * v1 + beta[c];
    ef[(size_t)q * 768 + 384 + c] = alpha[384 + c] * xcv + beta[384 + c];
}

// ---------------- cls rows: out[b,0,:] = x[b,0,:] + x_norm[b,0,:] ------------
__global__ void cls_kernel(const float* __restrict__ x,
                           const float* __restrict__ xn,
                           float* __restrict__ out) {
    int b = blockIdx.x;
    int c = threadIdx.x;
    size_t r = (size_t)b * 2049 * C384 + c;
    out[r] = x[r] + xn[r];
}

// ---------------- tiled fp32 GEMM: out = [res +] act(A@W + bias) -------------
// A: MxK row-major, W: KxN row-major. BM=BN=64, BK=16, 256 thr, 4x4 micro.
// REMAP: output/res row = m + (m>>11) + 1  (dense 8192 -> (b,1+n) in 2049-row x)
#define BM 64
#define BN 64
#define BK 16

template <bool GELU, bool REMAP, bool RES>
__global__ __launch_bounds__(256) void gemm_kernel(const float* __restrict__ A,
                                                   const float* __restrict__ W,
                                                   const float* __restrict__ bias,
                                                   const float* __restrict__ res,
                                                   float* __restrict__ out,
                                                   int M, int N, int K) {
    __shared__ float As[BK][BM];  // [kk][m]
    __shared__ float Bs[BK][BN];  // [kk][n]
    int tid = threadIdx.x;
    int tx = tid & 15, ty = tid >> 4;
    int bm = blockIdx.y * BM, bn = blockIdx.x * BN;

    int lm = tid >> 2;             // 0..63 : A row within tile
    int lk4 = (tid & 3) * 4;       // 0,4,8,12 : A k offset
    int lkk = tid >> 4;            // 0..15 : W k row
    int ln4 = (tid & 15) * 4;      // W col offset

    float acc[4][4] = {{0.f}};

    for (int k0 = 0; k0 < K; k0 += BK) {
        int gm = bm + lm;
        float4 av;
        if (gm < M)
            av = *(const float4*)(A + (size_t)gm * K + k0 + lk4);
        else
            av = make_float4(0.f, 0.f, 0.f, 0.f);
        float4 wv = *(const float4*)(W + (size_t)(k0 + lkk) * N + bn + ln4);
        As[lk4 + 0][lm] = av.x;
        As[lk4 + 1][lm] = av.y;
        As[lk4 + 2][lm] = av.z;
        As[lk4 + 3][lm] = av.w;
        *(float4*)&Bs[lkk][ln4] = wv;
        __syncthreads();
#pragma unroll
        for (int kk = 0; kk < BK; ++kk) {
            float4 a4 = *(const float4*)&As[kk][ty * 4];
            float4 b4 = *(const float4*)&Bs[kk][tx * 4];
            float a[4] = {a4.x, a4.y, a4.z, a4.w};
            float bb[4] = {b4.x, b4.y, b4.z, b4.w};
#pragma unroll
            for (int i = 0; i < 4; ++i)
#pragma unroll
                for (int j = 0; j < 4; ++j) acc[i][j] = fmaf(a[i], bb[j], acc[i][j]);
        }
        __syncthreads();
    }

    float4 bv = *(const float4*)(bias + bn + tx * 4);
    float bias4[4] = {bv.x, bv.y, bv.z, bv.w};
#pragma unroll
    for (int i = 0; i < 4; ++i) {
        int m = bm + ty * 4 + i;
        if (m >= M) continue;
        float v[4];
#pragma unroll
        for (int j = 0; j < 4; ++j) {
            v[j] = acc[i][j] + bias4[j];
            if (GELU) v[j] = gelu_exact(v[j]);
        }
        size_t orow = REMAP ? (size_t)(m + (m >> 11) + 1) : (size_t)m;
        size_t off = orow * (size_t)N + bn + tx * 4;
        if (RES) {
            float4 rv = *(const float4*)(res + off);
            v[0] += rv.x; v[1] += rv.y; v[2] += rv.z; v[3] += rv.w;
        }
        float4 ov = make_float4(v[0], v[1], v[2], v[3]);
        *(float4*)(out + off) = ov;
    }
}

// ---------------------------------------------------------------------------
extern "C" void kernel_launch(void* const* d_in, const int* in_sizes, int n_in,
                              void* d_out, int out_size, void* d_ws, size_t ws_size,
                              hipStream_t stream) {
    const float* center  = (const float*)d_in[0];
    const float* x       = (const float*)d_in[1];
    const float* ln1_g   = (const float*)d_in[2];
    const float* ln1_b   = (const float*)d_in[3];
    const float* alpha   = (const float*)d_in[4];
    const float* beta    = (const float*)d_in[5];
    const float* attn_w1 = (const float*)d_in[6];
    const float* attn_b1 = (const float*)d_in[7];
    const float* attn_w2 = (const float*)d_in[8];
    const float* attn_b2 = (const float*)d_in[9];
    const float* ln2_g   = (const float*)d_in[10];
    const float* ln2_b   = (const float*)d_in[11];
    const float* mlp_w1  = (const float*)d_in[12];
    const float* mlp_b1  = (const float*)d_in[13];
    const float* mlp_w2  = (const float*)d_in[14];
    const float* mlp_b2  = (const float*)d_in[15];
    float* out = (float*)d_out;

    // workspace layout (floats)
    float* ws = (float*)d_ws;
    float*  xn     = ws;                                   // 8196*384 = 3,147,264
    float*  sumknn = xn + 3147264;                         // 8192*384 = 3,145,728
    int*    idxb   = (int*)(sumknn + 3145728);             // 65,536 ints
    float2* part   = (float2*)(idxb + 65536);              // 8192 float2
    float*  stdbuf = (float*)(part + 8192);                // 4
    float*  ef     = stdbuf + 4;                           // 8192*768 = 6,291,456
    float*  h1     = ef + 6291456;                         // 8196*384 (h1 then y)
    float*  g      = ws;                                   // reuse: 8196*1536 fits below h1

    // 1. LN1: x (8196x384) -> xn
    ln_kernel<<<8196, 128, 0, stream>>>(x, xn, ln1_g, ln1_b);
    // 2. KNN indices
    knn_kernel<<<8192, 256, 0, stream>>>(center, idxb);
    // 3. gather neighbor sums + std partials
    gather_kernel<<<8192, 128, 0, stream>>>(xn, idxb, sumknn, part);
    // 4. global std -> inv scalar
    std_kernel<<<1, 256, 0, stream>>>(part, stdbuf);
    // 5. ef (8192x768)
    ef_kernel<<<8192, 384, 0, stream>>>(xn, sumknn, stdbuf, alpha, beta, ef);
    // 6. h1 = gelu(ef @ attn_w1 + b1)           (8192x384, K=768)
    gemm_kernel<true, false, false><<<dim3(384 / BN, (8192 + BM - 1) / BM), 256, 0, stream>>>(
        ef, attn_w1, attn_b1, nullptr, h1, 8192, 384, 768);
    // 7. out[b,1+n,:] = x + (h1 @ attn_w2 + b2) (remapped rows)
    gemm_kernel<false, true, true><<<dim3(384 / BN, (8192 + BM - 1) / BM), 256, 0, stream>>>(
        h1, attn_w2, attn_b2, x, out, 8192, 384, 384);
    // 7b. cls rows
    cls_kernel<<<4, 384, 0, stream>>>(x, xn, out);
    // 8. LN2: out -> y (reuse h1 buffer)
    ln_kernel<<<8196, 128, 0, stream>>>(out, h1, ln2_g, ln2_b);
    // 9. g = gelu(y @ mlp_w1 + b1)              (8196x1536, K=384)
    gemm_kernel<true, false, false><<<dim3(1536 / BN, (8196 + BM - 1) / BM), 256, 0, stream>>>(
        h1, mlp_w1, mlp_b1, nullptr, g, 8196, 1536, 384);
    // 10. out += g @ mlp_w2 + b2                (8196x384, K=1536)
    gemm_kernel<false, false, true><<<dim3(384 / BN, (8196 + BM - 1) / BM), 256, 0, stream>>>(
        g, mlp_w2, mlp_b2, out, out, 8196, 384, 1536);
}

// Round 2
// 270.666 us; speedup vs baseline: 2.0090x; 2.0090x over previous
//
#include <hip/hip_runtime.h>
#include <math.h>

// ---------------------------------------------------------------------------
// Mamba3DBlock forward. B=4, Npts=2048, C=384, K_GROUP=8. x rows = 8196.
// R2: GEMMs on bf16 MFMA (16x16x32), everything else fp32.
// ---------------------------------------------------------------------------

#define C384 384

typedef __attribute__((ext_vector_type(8))) short short8;
typedef __attribute__((ext_vector_type(4))) float f32x4;

__device__ __forceinline__ float gelu_exact(float v) {
    // jax.nn.gelu(approximate=False)
    return 0.5f * v * (1.0f + erff(v * 0.7071067811865475f));
}

__device__ __forceinline__ unsigned short f2bf(float f) {
    unsigned u = __float_as_uint(f);
    u += 0x7fffu + ((u >> 16) & 1u);   // round-to-nearest-even
    return (unsigned short)(u >> 16);
}

// ---------------- LayerNorm over last dim (C=384), one block per row --------
template <bool OUTBF>
__global__ __launch_bounds__(128) void ln_kernel(const float* __restrict__ in,
                                                 void* __restrict__ outp,
                                                 const float* __restrict__ g,
                                                 const float* __restrict__ b) {
    int row = blockIdx.x;
    int t = threadIdx.x;
    const float* x = in + (size_t)row * C384;
    float v0 = x[t], v1 = x[t + 128], v2 = x[t + 256];
    __shared__ float red[128];
    red[t] = v0 + v1 + v2;
    __syncthreads();
#pragma unroll
    for (int s = 64; s; s >>= 1) {
        if (t < s) red[t] += red[t + s];
        __syncthreads();
    }
    float m = red[0] / 384.0f;
    __syncthreads();
    float d0 = v0 - m, d1 = v1 - m, d2v = v2 - m;
    red[t] = d0 * d0 + d1 * d1 + d2v * d2v;
    __syncthreads();
#pragma unroll
    for (int s = 64; s; s >>= 1) {
        if (t < s) red[t] += red[t + s];
        __syncthreads();
    }
    float var = red[0] / 384.0f;
    float rstd = 1.0f / sqrtf(var + 1e-5f);
    float o0 = d0 * rstd * g[t] + b[t];
    float o1 = d1 * rstd * g[t + 128] + b[t + 128];
    float o2 = d2v * rstd * g[t + 256] + b[t + 256];
    if (OUTBF) {
        unsigned short* o = (unsigned short*)outp + (size_t)row * C384;
        o[t] = f2bf(o0); o[t + 128] = f2bf(o1); o[t + 256] = f2bf(o2);
    } else {
        float* o = (float*)outp + (size_t)row * C384;
        o[t] = o0; o[t + 128] = o1; o[t + 256] = o2;
    }
}

// ---------------- KNN: top-8 smallest d2, tie -> lower index ----------------
__global__ __launch_bounds__(256) void knn_kernel(const float* __restrict__ center,
                                                  int* __restrict__ idx_out) {
    int q = blockIdx.x;            // 0..8191  (b*2048 + n)
    int b = q >> 11, n = q & 2047;
    const float* cb = center + (size_t)b * 2048 * 3;
    float qx = cb[n * 3], qy = cb[n * 3 + 1], qz = cb[n * 3 + 2];
    float sqq = qx * qx + qy * qy + qz * qz;
    int t = threadIdx.x;
    unsigned long long key[8];
#pragma unroll
    for (int i = 0; i < 8; ++i) {
        int m = t + i * 256;
        float cx = cb[m * 3], cy = cb[m * 3 + 1], cz = cb[m * 3 + 2];
        float sqm = cx * cx + cy * cy + cz * cz;
        float dot = qx * cx + qy * cy + qz * cz;
        float d2 = (sqq + sqm) - 2.0f * dot;
        unsigned u = __float_as_uint(d2);
        u = (u & 0x80000000u) ? ~u : (u | 0x80000000u);
        key[i] = ((unsigned long long)u << 32) | (unsigned)m;
    }
    __shared__ unsigned long long red[256];
    for (int sel = 0; sel < 8; ++sel) {
        unsigned long long best = key[0];
#pragma unroll
        for (int i = 1; i < 8; ++i) best = (key[i] < best) ? key[i] : best;
        red[t] = best;
        __syncthreads();
#pragma unroll
        for (int s = 128; s; s >>= 1) {
            if (t < s) {
                unsigned long long o = red[t + s];
                if (o < red[t]) red[t] = o;
            }
            __syncthreads();
        }
        unsigned long long win = red[0];
        __syncthreads();
        if (t == 0) idx_out[(size_t)q * 8 + sel] = (int)(win & 0xffffffffu);
#pragma unroll
        for (int i = 0; i < 8; ++i)
            if (key[i] == win) key[i] = ~0ULL;
    }
}

// ---------------- gather 8 neighbors: sum_k x_no[idx_k][c], std partials ----
__global__ __launch_bounds__(128) void gather_kernel(const float* __restrict__ xn,
                                                     const int* __restrict__ idxb,
                                                     float* __restrict__ sumknn,
                                                     float2* __restrict__ part) {
    int q = blockIdx.x;
    int b = q >> 11;
    int t = threadIdx.x;
    __shared__ int sidx[8];
    if (t < 8) sidx[t] = idxb[(size_t)q * 8 + t];
    __syncthreads();
    const float* xno = xn + ((size_t)b * 2049 + 1) * C384;
    const float* xc  = xn + ((size_t)q + b + 1) * C384;
    float s1 = 0.f, s2 = 0.f;
    for (int c = t; c < C384; c += 128) {
        float xcv = xc[c];
        float acc = 0.f;
#pragma unroll
        for (int k = 0; k < 8; ++k) {
            float v = xno[(size_t)sidx[k] * C384 + c];
            acc += v;
            float d = v - xcv;
            s1 += d;
            s2 += d * d;
        }
        sumknn[(size_t)q * C384 + c] = acc;
    }
    __shared__ float r1[128], r2[128];
    r1[t] = s1; r2[t] = s2;
    __syncthreads();
#pragma unroll
    for (int s = 64; s; s >>= 1) {
        if (t < s) { r1[t] += r1[t + s]; r2[t] += r2[t + s]; }
        __syncthreads();
    }
    if (t == 0) part[q] = make_float2(r1[0], r2[0]);
}

// ---------------- reduce std partials -> inv = 1/(std+1e-5) -----------------
__global__ __launch_bounds__(256) void std_kernel(const float2* __restrict__ part,
                                                  float* __restrict__ stdbuf) {
    int t = threadIdx.x;
    double s1 = 0.0, s2 = 0.0;
    for (int i = t; i < 8192; i += 256) {
        float2 p = part[i];
        s1 += (double)p.x;
        s2 += (double)p.y;
    }
    __shared__ double r1[256], r2[256];
    r1[t] = s1; r2[t] = s2;
    __syncthreads();
#pragma unroll
    for (int s = 128; s; s >>= 1) {
        if (t < s) { r1[t] += r1[t + s]; r2[t] += r2[t + s]; }
        __syncthreads();
    }
    if (t == 0) {
        const double N = 25165824.0;
        double var = (r2[0] - r1[0] * r1[0] / N) / (N - 1.0);
        float stdf = (float)sqrt(var);
        stdbuf[0] = 1.0f / (stdf + 1e-5f);
    }
}

// ---------------- build ef (8192 x 768) bf16 ---------------------------------
__global__ __launch_bounds__(384) void ef_kernel(const float* __restrict__ xn,
                                                 const float* __restrict__ sumknn,
                                                 const float* __restrict__ stdbuf,
                                                 const float* __restrict__ alpha,
                                                 const float* __restrict__ beta,
                                                 unsigned short* __restrict__ ef) {
    int q = blockIdx.x;
    int b = q >> 11;
    int c = threadIdx.x;
    float inv = stdbuf[0];
    float xcv = xn[((size_t)q + b + 1) * C384 + c];
    float mk = sumknn[(size_t)q * C384 + c] * 0.125f;
    float v1 = (mk - xcv) * inv;
    ef[(size_t)q * 768 + c]       = f2bf(alpha[c] * v1 + beta[c]);
    ef[(size_t)q * 768 + 384 + c] = f2bf(alpha[384 + c] * xcv + beta[384 + c]);
}

// ---------------- cls rows: out[b,0,:] = x[b,0,:] + x_norm[b,0,:] ------------
__global__ void cls_kernel(const float* __restrict__ x,
                           const float* __restrict__ xn,
                           float* __restrict__ out) {
    int b = blockIdx.x;
    int c = threadIdx.x;
    size_t r = (size_t)b * 2049 * C384 + c;
    out[r] = x[r] + xn[r];
}

// ---------------- transpose + cast: outT[n][k] = bf16(in[k][n]) --------------
// K,N multiples of 32. 256 threads, 32x32 tile.
__global__ __launch_bounds__(256) void tcast_kernel(const float* __restrict__ in,
                                                    unsigned short* __restrict__ outT,
                                                    int K, int N) {
    __shared__ float tile[32][33];
    int kb = blockIdx.y * 32, nb = blockIdx.x * 32;
    int c = threadIdx.x & 31, r0 = threadIdx.x >> 5;
#pragma unroll
    for (int i = 0; i < 4; ++i) {
        int r = r0 + i * 8;
        tile[r][c] = in[(size_t)(kb + r) * N + nb + c];
    }
    __syncthreads();
#pragma unroll
    for (int i = 0; i < 4; ++i) {
        int r = r0 + i * 8;               // n-local
        outT[(size_t)(nb + r) * K + kb + c] = f2bf(tile[c][r]);
    }
}

// ---------------- bf16 MFMA GEMM ---------------------------------------------
// A:  M x K bf16 row-major.  Bt: N x K bf16 row-major (i.e. B transposed).
// out = [res +] act(A@B + bias).  128x128 tile, BK=64, 4 waves (64x64 each).
// LDS XOR swizzle (row&7)<<4 on 16B chunks -> ~2-way conflicts (free).
#define GBM 128
#define GBN 128
#define GBK 64

template <bool GELU, bool REMAP, bool RES, bool OUTBF>
__global__ __launch_bounds__(256) void mfma_gemm(const unsigned short* __restrict__ A,
                                                 const unsigned short* __restrict__ Bt,
                                                 const float* __restrict__ bias,
                                                 const float* __restrict__ res,
                                                 void* __restrict__ outp,
                                                 int M, int N, int K) {
    __shared__ char smem[32768];
    char* smA = smem;
    char* smB = smem + 16384;
    int t = threadIdx.x;
    int lane = t & 63, w = t >> 6;
    int wr = w >> 1, wc = w & 1;
    int bm = blockIdx.y * GBM, bn = blockIdx.x * GBN;

    f32x4 acc[4][4] = {};

    int srow = t >> 3;      // 0..31
    int sc16 = t & 7;       // 16B chunk within 128B row

    for (int k0 = 0; k0 < K; k0 += GBK) {
        __syncthreads();
#pragma unroll
        for (int p = 0; p < 4; ++p) {
            int row = srow + p * 32;
            int swz = (sc16 ^ (row & 7)) << 4;
            uint4 va = make_uint4(0u, 0u, 0u, 0u);
            int gm = bm + row;
            if (gm < M) va = *(const uint4*)(A + (size_t)gm * K + k0 + sc16 * 8);
            *(uint4*)(smA + row * 128 + swz) = va;
            uint4 vb = *(const uint4*)(Bt + (size_t)(bn + row) * K + k0 + sc16 * 8);
            *(uint4*)(smB + row * 128 + swz) = vb;
        }
        __syncthreads();
#pragma unroll
        for (int ks = 0; ks < 2; ++ks) {
            short8 af[4], bfr[4];
            int cb = ks * 4 + (lane >> 4);
#pragma unroll
            for (int mi = 0; mi < 4; ++mi) {
                int row = wr * 64 + mi * 16 + (lane & 15);
                af[mi] = *(const short8*)(smA + row * 128 + ((cb ^ (row & 7)) << 4));
            }
#pragma unroll
            for (int nj = 0; nj < 4; ++nj) {
                int row = wc * 64 + nj * 16 + (lane & 15);
                bfr[nj] = *(const short8*)(smB + row * 128 + ((cb ^ (row & 7)) << 4));
            }
#pragma unroll
            for (int mi = 0; mi < 4; ++mi)
#pragma unroll
                for (int nj = 0; nj < 4; ++nj)
                    acc[mi][nj] = __builtin_amdgcn_mfma_f32_16x16x32_bf16(
                        af[mi], bfr[nj], acc[mi][nj], 0, 0, 0);
        }
    }

    // epilogue: C/D layout col=lane&15, row=(lane>>4)*4+reg
#pragma unroll
    for (int nj = 0; nj < 4; ++nj) {
        int n = bn + wc * 64 + nj * 16 + (lane & 15);
        float bs = bias[n];
#pragma unroll
        for (int mi = 0; mi < 4; ++mi) {
#pragma unroll
            for (int r = 0; r < 4; ++r) {
                int m = bm + wr * 64 + mi * 16 + (lane >> 4) * 4 + r;
                if (m >= M) continue;
                float v = acc[mi][nj][r] + bs;
                if (GELU) v = gelu_exact(v);
                size_t orow = REMAP ? (size_t)(m + (m >> 11) + 1) : (size_t)m;
                size_t off = orow * (size_t)N + n;
                if (RES) v += res[off];
                if (OUTBF)
                    ((unsigned short*)outp)[(size_t)m * N + n] = f2bf(v);
                else
                    ((float*)outp)[off] = v;
            }
        }
    }
}

// ---------------------------------------------------------------------------
extern "C" void kernel_launch(void* const* d_in, const int* in_sizes, int n_in,
                              void* d_out, int out_size, void* d_ws, size_t ws_size,
                              hipStream_t stream) {
    const float* center  = (const float*)d_in[0];
    const float* x       = (const float*)d_in[1];
    const float* ln1_g   = (const float*)d_in[2];
    const float* ln1_b   = (const float*)d_in[3];
    const float* alpha   = (const float*)d_in[4];
    const float* beta    = (const float*)d_in[5];
    const float* attn_w1 = (const float*)d_in[6];
    const float* attn_b1 = (const float*)d_in[7];
    const float* attn_w2 = (const float*)d_in[8];
    const float* attn_b2 = (const float*)d_in[9];
    const float* ln2_g   = (const float*)d_in[10];
    const float* ln2_b   = (const float*)d_in[11];
    const float* mlp_w1  = (const float*)d_in[12];
    const float* mlp_b1  = (const float*)d_in[13];
    const float* mlp_w2  = (const float*)d_in[14];
    const float* mlp_b2  = (const float*)d_in[15];
    float* out = (float*)d_out;

    // workspace layout (bytes, all 256-aligned)
    char* wsb = (char*)d_ws;
    float*          xn     = (float*)(wsb + 0);           // 12,589,056
    float*          sumknn = (float*)(wsb + 12589056);    // 12,582,912
    int*            idxb   = (int*)(wsb + 25171968);      // 262,144
    float2*         part   = (float2*)(wsb + 25434112);   // 65,536
    unsigned short* ef     = (unsigned short*)(wsb + 25499648); // 12,582,912 -> ends 38,082,560
    unsigned short* g      = (unsigned short*)(wsb + 12589056); // overlay (sumknn..ef dead): 25,178,112 -> ends 37,767,168
    unsigned short* h1     = (unsigned short*)(wsb + 38082560); // 6,291,456
    unsigned short* yb     = (unsigned short*)(wsb + 44374016); // 6,294,528
    float*          stdbuf = (float*)(wsb + 50668544);
    unsigned short* w1T    = (unsigned short*)(wsb + 50668800); // 384x768
    unsigned short* w2T    = (unsigned short*)(wsb + 51258624); // 384x384
    unsigned short* mw1T   = (unsigned short*)(wsb + 51553536); // 1536x384
    unsigned short* mw2T   = (unsigned short*)(wsb + 52733184); // 384x1536

    // 0. weight transpose+cast to bf16 [N][K]
    tcast_kernel<<<dim3(384 / 32, 768 / 32), 256, 0, stream>>>(attn_w1, w1T, 768, 384);
    tcast_kernel<<<dim3(384 / 32, 384 / 32), 256, 0, stream>>>(attn_w2, w2T, 384, 384);
    tcast_kernel<<<dim3(1536 / 32, 384 / 32), 256, 0, stream>>>(mlp_w1, mw1T, 384, 1536);
    tcast_kernel<<<dim3(384 / 32, 1536 / 32), 256, 0, stream>>>(mlp_w2, mw2T, 1536, 384);
    // 1. LN1 (f32 out)
    ln_kernel<false><<<8196, 128, 0, stream>>>(x, xn, ln1_g, ln1_b);
    // 2. KNN
    knn_kernel<<<8192, 256, 0, stream>>>(center, idxb);
    // 3. gather
    gather_kernel<<<8192, 128, 0, stream>>>(xn, idxb, sumknn, part);
    // 4. std
    std_kernel<<<1, 256, 0, stream>>>(part, stdbuf);
    // 5. ef (bf16)
    ef_kernel<<<8192, 384, 0, stream>>>(xn, sumknn, stdbuf, alpha, beta, ef);
    // 6. h1 = gelu(ef @ attn_w1 + b1)   M=8192 N=384 K=768, bf16 out
    mfma_gemm<true, false, false, true><<<dim3(3, 64), 256, 0, stream>>>(
        ef, w1T, attn_b1, nullptr, h1, 8192, 384, 768);
    // 7. out[remap] = x + h1 @ attn_w2 + b2   M=8192 N=384 K=384, f32 out
    mfma_gemm<false, true, true, false><<<dim3(3, 64), 256, 0, stream>>>(
        h1, w2T, attn_b2, x, out, 8192, 384, 384);
    // 7b. cls rows
    cls_kernel<<<4, 384, 0, stream>>>(x, xn, out);
    // 8. LN2 -> y bf16
    ln_kernel<true><<<8196, 128, 0, stream>>>(out, yb, ln2_g, ln2_b);
    // 9. g = gelu(y @ mlp_w1 + b1)   M=8196 N=1536 K=384, bf16 out
    mfma_gemm<true, false, false, true><<<dim3(12, 65), 256, 0, stream>>>(
        yb, mw1T, mlp_b1, nullptr, g, 8196, 1536, 384);
    // 10. out += g @ mlp_w2 + b2   M=8196 N=384 K=1536, f32 out
    mfma_gemm<false, false, true, false><<<dim3(3, 65), 256, 0, stream>>>(
        g, mw2T, mlp_b2, out, out, 8196, 384, 1536);
}

// Round 3
// 189.424 us; speedup vs baseline: 2.8706x; 1.4289x over previous
//
#include <hip/hip_runtime.h>
#include <math.h>

// ---------------------------------------------------------------------------
// Mamba3DBlock forward. B=4, Npts=2048, C=384, K_GROUP=8. x rows = 8196.
// R3: 64x64 MFMA tiles (occupancy fix), wave-parallel KNN, merged tcast.
// ---------------------------------------------------------------------------

#define C384 384

typedef __attribute__((ext_vector_type(8))) short short8;
typedef __attribute__((ext_vector_type(4))) float f32x4;

__device__ __forceinline__ float gelu_exact(float v) {
    return 0.5f * v * (1.0f + erff(v * 0.7071067811865475f));
}

__device__ __forceinline__ unsigned short f2bf(float f) {
    unsigned u = __float_as_uint(f);
    u += 0x7fffu + ((u >> 16) & 1u);
    return (unsigned short)(u >> 16);
}

__device__ __forceinline__ unsigned long long shfl_xor_u64(unsigned long long v, int m) {
    int lo = __shfl_xor((int)(unsigned)v, m, 64);
    int hi = __shfl_xor((int)(unsigned)(v >> 32), m, 64);
    return ((unsigned long long)(unsigned)hi << 32) | (unsigned)lo;
}

// ---------------- LayerNorm over last dim (C=384), one block per row --------
template <bool OUTBF>
__global__ __launch_bounds__(128) void ln_kernel(const float* __restrict__ in,
                                                 void* __restrict__ outp,
                                                 const float* __restrict__ g,
                                                 const float* __restrict__ b) {
    int row = blockIdx.x;
    int t = threadIdx.x;
    const float* x = in + (size_t)row * C384;
    float v0 = x[t], v1 = x[t + 128], v2 = x[t + 256];
    __shared__ float red[128];
    red[t] = v0 + v1 + v2;
    __syncthreads();
#pragma unroll
    for (int s = 64; s; s >>= 1) {
        if (t < s) red[t] += red[t + s];
        __syncthreads();
    }
    float m = red[0] / 384.0f;
    __syncthreads();
    float d0 = v0 - m, d1 = v1 - m, d2v = v2 - m;
    red[t] = d0 * d0 + d1 * d1 + d2v * d2v;
    __syncthreads();
#pragma unroll
    for (int s = 64; s; s >>= 1) {
        if (t < s) red[t] += red[t + s];
        __syncthreads();
    }
    float var = red[0] / 384.0f;
    float rstd = 1.0f / sqrtf(var + 1e-5f);
    float o0 = d0 * rstd * g[t] + b[t];
    float o1 = d1 * rstd * g[t + 128] + b[t + 128];
    float o2 = d2v * rstd * g[t + 256] + b[t + 256];
    if (OUTBF) {
        unsigned short* o = (unsigned short*)outp + (size_t)row * C384;
        o[t] = f2bf(o0); o[t + 128] = f2bf(o1); o[t + 256] = f2bf(o2);
    } else {
        float* o = (float*)outp + (size_t)row * C384;
        o[t] = o0; o[t + 128] = o1; o[t + 256] = o2;
    }
}

// ---------------- KNN: one wave per query, zero barriers --------------------
// top-8 smallest d2, tie -> lower index (packed u64 key preserves both).
__global__ __launch_bounds__(256) void knn_kernel(const float* __restrict__ center,
                                                  int* __restrict__ idx_out) {
    int w = threadIdx.x >> 6;
    int l = threadIdx.x & 63;
    int q = blockIdx.x * 4 + w;      // 0..8191
    int b = q >> 11, n = q & 2047;
    const float* cb = center + (size_t)b * 2048 * 3;
    float qx = cb[n * 3], qy = cb[n * 3 + 1], qz = cb[n * 3 + 2];
    float sqq = qx * qx + qy * qy + qz * qz;
    unsigned long long key[32];
#pragma unroll
    for (int i = 0; i < 32; ++i) {
        int m = l + i * 64;
        float cx = cb[m * 3], cy = cb[m * 3 + 1], cz = cb[m * 3 + 2];
        float sqm = cx * cx + cy * cy + cz * cz;
        float dot = qx * cx + qy * cy + qz * cz;
        float d2 = (sqq + sqm) - 2.0f * dot;
        unsigned u = __float_as_uint(d2);
        u = (u & 0x80000000u) ? ~u : (u | 0x80000000u);
        key[i] = ((unsigned long long)u << 32) | (unsigned)m;
    }
    for (int sel = 0; sel < 8; ++sel) {
        unsigned long long best = key[0];
#pragma unroll
        for (int i = 1; i < 32; ++i) best = (key[i] < best) ? key[i] : best;
#pragma unroll
        for (int off = 32; off; off >>= 1) {
            unsigned long long o = shfl_xor_u64(best, off);
            best = (o < best) ? o : best;
        }
        if (l == 0) idx_out[(size_t)q * 8 + sel] = (int)(best & 0xffffffffu);
#pragma unroll
        for (int i = 0; i < 32; ++i)
            if (key[i] == best) key[i] = ~0ULL;
    }
}

// ---------------- gather 8 neighbors: sum_k x_no[idx_k][c], std partials ----
__global__ __launch_bounds__(128) void gather_kernel(const float* __restrict__ xn,
                                                     const int* __restrict__ idxb,
                                                     float* __restrict__ sumknn,
                                                     float2* __restrict__ part) {
    int q = blockIdx.x;
    int b = q >> 11;
    int t = threadIdx.x;
    __shared__ int sidx[8];
    if (t < 8) sidx[t] = idxb[(size_t)q * 8 + t];
    __syncthreads();
    const float* xno = xn + ((size_t)b * 2049 + 1) * C384;
    const float* xc  = xn + ((size_t)q + b + 1) * C384;
    float s1 = 0.f, s2 = 0.f;
    for (int c = t; c < C384; c += 128) {
        float xcv = xc[c];
        float acc = 0.f;
#pragma unroll
        for (int k = 0; k < 8; ++k) {
            float v = xno[(size_t)sidx[k] * C384 + c];
            acc += v;
            float d = v - xcv;
            s1 += d;
            s2 += d * d;
        }
        sumknn[(size_t)q * C384 + c] = acc;
    }
    __shared__ float r1[128], r2[128];
    r1[t] = s1; r2[t] = s2;
    __syncthreads();
#pragma unroll
    for (int s = 64; s; s >>= 1) {
        if (t < s) { r1[t] += r1[t + s]; r2[t] += r2[t + s]; }
        __syncthreads();
    }
    if (t == 0) part[q] = make_float2(r1[0], r2[0]);
}

// ---------------- reduce std partials -> inv = 1/(std+1e-5) -----------------
__global__ __launch_bounds__(256) void std_kernel(const float2* __restrict__ part,
                                                  float* __restrict__ stdbuf) {
    int t = threadIdx.x;
    double s1 = 0.0, s2 = 0.0;
    for (int i = t; i < 8192; i += 256) {
        float2 p = part[i];
        s1 += (double)p.x;
        s2 += (double)p.y;
    }
    __shared__ double r1[256], r2[256];
    r1[t] = s1; r2[t] = s2;
    __syncthreads();
#pragma unroll
    for (int s = 128; s; s >>= 1) {
        if (t < s) { r1[t] += r1[t + s]; r2[t] += r2[t + s]; }
        __syncthreads();
    }
    if (t == 0) {
        const double N = 25165824.0;
        double var = (r2[0] - r1[0] * r1[0] / N) / (N - 1.0);
        float stdf = (float)sqrt(var);
        stdbuf[0] = 1.0f / (stdf + 1e-5f);
    }
}

// ---------------- build ef (8192 x 768) bf16 ---------------------------------
__global__ __launch_bounds__(384) void ef_kernel(const float* __restrict__ xn,
                                                 const float* __restrict__ sumknn,
                                                 const float* __restrict__ stdbuf,
                                                 const float* __restrict__ alpha,
                                                 const float* __restrict__ beta,
                                                 unsigned short* __restrict__ ef) {
    int q = blockIdx.x;
    int b = q >> 11;
    int c = threadIdx.x;
    float inv = stdbuf[0];
    float xcv = xn[((size_t)q + b + 1) * C384 + c];
    float mk = sumknn[(size_t)q * C384 + c] * 0.125f;
    float v1 = (mk - xcv) * inv;
    ef[(size_t)q * 768 + c]       = f2bf(alpha[c] * v1 + beta[c]);
    ef[(size_t)q * 768 + 384 + c] = f2bf(alpha[384 + c] * xcv + beta[384 + c]);
}

// ---------------- cls rows ----------------------------------------------------
__global__ void cls_kernel(const float* __restrict__ x,
                           const float* __restrict__ xn,
                           float* __restrict__ out) {
    int b = blockIdx.x;
    int c = threadIdx.x;
    size_t r = (size_t)b * 2049 * C384 + c;
    out[r] = x[r] + xn[r];
}

// ---------------- all 4 weight transposes in one launch ----------------------
// outT[n][k] = bf16(in[k][n]); 32x32 tiles, tile id ranges select matrix.
__global__ __launch_bounds__(256) void tcast4_kernel(const float* __restrict__ w1,
                                                     const float* __restrict__ w2,
                                                     const float* __restrict__ m1,
                                                     const float* __restrict__ m2,
                                                     unsigned short* __restrict__ o1,
                                                     unsigned short* __restrict__ o2,
                                                     unsigned short* __restrict__ o3,
                                                     unsigned short* __restrict__ o4) {
    int tid = blockIdx.x;
    const float* in; unsigned short* outp; int K, N, local;
    if (tid < 288)       { in = w1; outp = o1; K = 768;  N = 384;  local = tid; }
    else if (tid < 432)  { in = w2; outp = o2; K = 384;  N = 384;  local = tid - 288; }
    else if (tid < 1008) { in = m1; outp = o3; K = 384;  N = 1536; local = tid - 432; }
    else                 { in = m2; outp = o4; K = 1536; N = 384;  local = tid - 1008; }
    int ntN = N >> 5;
    int kb = (local / ntN) * 32, nb = (local % ntN) * 32;
    __shared__ float tile[32][33];
    int c = threadIdx.x & 31, r0 = threadIdx.x >> 5;
#pragma unroll
    for (int i = 0; i < 4; ++i) {
        int r = r0 + i * 8;
        tile[r][c] = in[(size_t)(kb + r) * N + nb + c];
    }
    __syncthreads();
#pragma unroll
    for (int i = 0; i < 4; ++i) {
        int r = r0 + i * 8;
        outp[(size_t)(nb + r) * K + kb + c] = f2bf(tile[c][r]);
    }
}

// ---------------- bf16 MFMA GEMM, 64x64 tile, BK=64, 4 waves (32x32 each) ----
// A: M x K bf16 row-major. Bt: N x K bf16 row-major. out = [res+] act(A@B+bias)
// LDS XOR swizzle (row&7) on 16B chunks -> conflict-free (verified R2: 0).
template <bool GELU, bool REMAP, bool RES, bool OUTBF>
__global__ __launch_bounds__(256) void mfma_gemm(const unsigned short* __restrict__ A,
                                                 const unsigned short* __restrict__ Bt,
                                                 const float* __restrict__ bias,
                                                 const float* __restrict__ res,
                                                 void* __restrict__ outp,
                                                 int M, int N, int K) {
    __shared__ char smem[16384];
    char* smA = smem;           // 64 rows x 128B
    char* smB = smem + 8192;    // 64 rows x 128B
    int t = threadIdx.x;
    int lane = t & 63, w = t >> 6;
    int wr = w >> 1, wc = w & 1;       // 2x2 waves, each 32x32
    int bm = blockIdx.y * 64, bn = blockIdx.x * 64;

    f32x4 acc[2][2] = {};

    int srow = t >> 3;      // 0..31 (row pair base)
    int sc16 = t & 7;       // 16B chunk in 128B row

    for (int k0 = 0; k0 < K; k0 += 64) {
        __syncthreads();
#pragma unroll
        for (int p = 0; p < 2; ++p) {
            int row = srow + p * 32;
            int swz = (sc16 ^ (row & 7)) << 4;
            uint4 va = make_uint4(0u, 0u, 0u, 0u);
            int gm = bm + row;
            if (gm < M) va = *(const uint4*)(A + (size_t)gm * K + k0 + sc16 * 8);
            *(uint4*)(smA + row * 128 + swz) = va;
            uint4 vb = *(const uint4*)(Bt + (size_t)(bn + row) * K + k0 + sc16 * 8);
            *(uint4*)(smB + row * 128 + swz) = vb;
        }
        __syncthreads();
#pragma unroll
        for (int ks = 0; ks < 2; ++ks) {
            short8 af[2], bfr[2];
            int cb = ks * 4 + (lane >> 4);
#pragma unroll
            for (int mi = 0; mi < 2; ++mi) {
                int row = wr * 32 + mi * 16 + (lane & 15);
                af[mi] = *(const short8*)(smA + row * 128 + ((cb ^ (row & 7)) << 4));
            }
#pragma unroll
            for (int nj = 0; nj < 2; ++nj) {
                int row = wc * 32 + nj * 16 + (lane & 15);
                bfr[nj] = *(const short8*)(smB + row * 128 + ((cb ^ (row & 7)) << 4));
            }
#pragma unroll
            for (int mi = 0; mi < 2; ++mi)
#pragma unroll
                for (int nj = 0; nj < 2; ++nj)
                    acc[mi][nj] = __builtin_amdgcn_mfma_f32_16x16x32_bf16(
                        af[mi], bfr[nj], acc[mi][nj], 0, 0, 0);
        }
    }

    // epilogue: C/D layout col=lane&15, row=(lane>>4)*4+reg
#pragma unroll
    for (int nj = 0; nj < 2; ++nj) {
        int n = bn + wc * 32 + nj * 16 + (lane & 15);
        float bs = bias[n];
#pragma unroll
        for (int mi = 0; mi < 2; ++mi) {
#pragma unroll
            for (int r = 0; r < 4; ++r) {
                int m = bm + wr * 32 + mi * 16 + (lane >> 4) * 4 + r;
                if (m >= M) continue;
                float v = acc[mi][nj][r] + bs;
                if (GELU) v = gelu_exact(v);
                size_t orow = REMAP ? (size_t)(m + (m >> 11) + 1) : (size_t)m;
                size_t off = orow * (size_t)N + n;
                if (RES) v += res[off];
                if (OUTBF)
                    ((unsigned short*)outp)[(size_t)m * N + n] = f2bf(v);
                else
                    ((float*)outp)[off] = v;
            }
        }
    }
}

// ---------------------------------------------------------------------------
extern "C" void kernel_launch(void* const* d_in, const int* in_sizes, int n_in,
                              void* d_out, int out_size, void* d_ws, size_t ws_size,
                              hipStream_t stream) {
    const float* center  = (const float*)d_in[0];
    const float* x       = (const float*)d_in[1];
    const float* ln1_g   = (const float*)d_in[2];
    const float* ln1_b   = (const float*)d_in[3];
    const float* alpha   = (const float*)d_in[4];
    const float* beta    = (const float*)d_in[5];
    const float* attn_w1 = (const float*)d_in[6];
    const float* attn_b1 = (const float*)d_in[7];
    const float* attn_w2 = (const float*)d_in[8];
    const float* attn_b2 = (const float*)d_in[9];
    const float* ln2_g   = (const float*)d_in[10];
    const float* ln2_b   = (const float*)d_in[11];
    const float* mlp_w1  = (const float*)d_in[12];
    const float* mlp_b1  = (const float*)d_in[13];
    const float* mlp_w2  = (const float*)d_in[14];
    const float* mlp_b2  = (const float*)d_in[15];
    float* out = (float*)d_out;

    // workspace layout (bytes, all 256-aligned)
    char* wsb = (char*)d_ws;
    float*          xn     = (float*)(wsb + 0);                  // 12,589,056
    float*          sumknn = (float*)(wsb + 12589056);           // 12,582,912
    int*            idxb   = (int*)(wsb + 25171968);             // 262,144
    float2*         part   = (float2*)(wsb + 25434112);          // 65,536
    unsigned short* ef     = (unsigned short*)(wsb + 25499648);  // 12,582,912 -> ends 38,082,560
    unsigned short* g      = (unsigned short*)(wsb + 12589056);  // overlay: 25,178,112 -> ends 37,767,168
    unsigned short* h1     = (unsigned short*)(wsb + 38082560);  // 6,291,456
    unsigned short* yb     = (unsigned short*)(wsb + 44374016);  // 6,294,528
    float*          stdbuf = (float*)(wsb + 50668544);
    unsigned short* w1T    = (unsigned short*)(wsb + 50668800);  // 384x768
    unsigned short* w2T    = (unsigned short*)(wsb + 51258624);  // 384x384
    unsigned short* mw1T   = (unsigned short*)(wsb + 51553536);  // 1536x384
    unsigned short* mw2T   = (unsigned short*)(wsb + 52733184);  // 384x1536

    // 0. weight transpose+cast (one launch)
    tcast4_kernel<<<1584, 256, 0, stream>>>(attn_w1, attn_w2, mlp_w1, mlp_w2,
                                            w1T, w2T, mw1T, mw2T);
    // 1. LN1 (f32 out)
    ln_kernel<false><<<8196, 128, 0, stream>>>(x, xn, ln1_g, ln1_b);
    // 2. KNN (wave per query)
    knn_kernel<<<2048, 256, 0, stream>>>(center, idxb);
    // 3. gather
    gather_kernel<<<8192, 128, 0, stream>>>(xn, idxb, sumknn, part);
    // 4. std
    std_kernel<<<1, 256, 0, stream>>>(part, stdbuf);
    // 5. ef (bf16)
    ef_kernel<<<8192, 384, 0, stream>>>(xn, sumknn, stdbuf, alpha, beta, ef);
    // 6. h1 = gelu(ef @ attn_w1 + b1)   M=8192 N=384 K=768
    mfma_gemm<true, false, false, true><<<dim3(6, 128), 256, 0, stream>>>(
        ef, w1T, attn_b1, nullptr, h1, 8192, 384, 768);
    // 7. out[remap] = x + h1 @ attn_w2 + b2   M=8192 N=384 K=384
    mfma_gemm<false, true, true, false><<<dim3(6, 128), 256, 0, stream>>>(
        h1, w2T, attn_b2, x, out, 8192, 384, 384);
    // 7b. cls rows
    cls_kernel<<<4, 384, 0, stream>>>(x, xn, out);
    // 8. LN2 -> y bf16
    ln_kernel<true><<<8196, 128, 0, stream>>>(out, yb, ln2_g, ln2_b);
    // 9. g = gelu(y @ mlp_w1 + b1)   M=8196 N=1536 K=384
    mfma_gemm<true, false, false, true><<<dim3(24, 129), 256, 0, stream>>>(
        yb, mw1T, mlp_b1, nullptr, g, 8196, 1536, 384);
    // 10. out += g @ mlp_w2 + b2   M=8196 N=384 K=1536
    mfma_gemm<false, false, true, false><<<dim3(6, 129), 256, 0, stream>>>(
        g, mw2T, mlp_b2, out, out, 8196, 384, 1536);
}

// Round 4
// 184.352 us; speedup vs baseline: 2.9496x; 1.0275x over previous
//
#include <hip/hip_runtime.h>
#include <math.h>

// ---------------------------------------------------------------------------
// Mamba3DBlock forward. B=4, Npts=2048, C=384, K_GROUP=8. x rows = 8196.
// R4: hierarchical KNN selection (group-min cache + execz-skipped repair),
//     double-buffered GEMM with early global-load issue (1 barrier/K-tile).
// ---------------------------------------------------------------------------

#define C384 384

typedef __attribute__((ext_vector_type(8))) short short8;
typedef __attribute__((ext_vector_type(4))) float f32x4;

__device__ __forceinline__ float gelu_exact(float v) {
    return 0.5f * v * (1.0f + erff(v * 0.7071067811865475f));
}

__device__ __forceinline__ unsigned short f2bf(float f) {
    unsigned u = __float_as_uint(f);
    u += 0x7fffu + ((u >> 16) & 1u);
    return (unsigned short)(u >> 16);
}

__device__ __forceinline__ unsigned long long shfl_xor_u64(unsigned long long v, int m) {
    int lo = __shfl_xor((int)(unsigned)v, m, 64);
    int hi = __shfl_xor((int)(unsigned)(v >> 32), m, 64);
    return ((unsigned long long)(unsigned)hi << 32) | (unsigned)lo;
}

// ---------------- LayerNorm over last dim (C=384), one block per row --------
template <bool OUTBF>
__global__ __launch_bounds__(128) void ln_kernel(const float* __restrict__ in,
                                                 void* __restrict__ outp,
                                                 const float* __restrict__ g,
                                                 const float* __restrict__ b) {
    int row = blockIdx.x;
    int t = threadIdx.x;
    const float* x = in + (size_t)row * C384;
    float v0 = x[t], v1 = x[t + 128], v2 = x[t + 256];
    __shared__ float red[128];
    red[t] = v0 + v1 + v2;
    __syncthreads();
#pragma unroll
    for (int s = 64; s; s >>= 1) {
        if (t < s) red[t] += red[t + s];
        __syncthreads();
    }
    float m = red[0] / 384.0f;
    __syncthreads();
    float d0 = v0 - m, d1 = v1 - m, d2v = v2 - m;
    red[t] = d0 * d0 + d1 * d1 + d2v * d2v;
    __syncthreads();
#pragma unroll
    for (int s = 64; s; s >>= 1) {
        if (t < s) red[t] += red[t + s];
        __syncthreads();
    }
    float var = red[0] / 384.0f;
    float rstd = 1.0f / sqrtf(var + 1e-5f);
    float o0 = d0 * rstd * g[t] + b[t];
    float o1 = d1 * rstd * g[t + 128] + b[t + 128];
    float o2 = d2v * rstd * g[t + 256] + b[t + 256];
    if (OUTBF) {
        unsigned short* o = (unsigned short*)outp + (size_t)row * C384;
        o[t] = f2bf(o0); o[t + 128] = f2bf(o1); o[t + 256] = f2bf(o2);
    } else {
        float* o = (float*)outp + (size_t)row * C384;
        o[t] = o0; o[t + 128] = o1; o[t + 256] = o2;
    }
}

// ---------------- KNN: one wave per query, hierarchical selection ------------
// keys: u64 = ordered(d2)<<32 | m (unique -> exact tie-break by lower index).
// Per lane: 32 keys in 8 groups of 4; cached group-mins gm[8] + lane-min lm.
// Per pass: wave-argmin(lm); the single winner lane repairs its dirty group
// (7/8 groups skipped via s_cbranch_execz; asm clobber forces real branches).
__global__ __launch_bounds__(256) void knn_kernel(const float* __restrict__ center,
                                                  int* __restrict__ idx_out) {
    int w = threadIdx.x >> 6;
    int l = threadIdx.x & 63;
    int q = blockIdx.x * 4 + w;      // 0..8191
    int b = q >> 11, n = q & 2047;
    const float* cb = center + (size_t)b * 2048 * 3;
    float qx = cb[n * 3], qy = cb[n * 3 + 1], qz = cb[n * 3 + 2];
    float sqq = qx * qx + qy * qy + qz * qz;
    unsigned long long key[32], gm[8];
#pragma unroll
    for (int g = 0; g < 8; ++g) {
        unsigned long long kmin = ~0ULL;
#pragma unroll
        for (int j = 0; j < 4; ++j) {
            int i = g * 4 + j;
            int m = i * 64 + l;
            float cx = cb[m * 3], cy = cb[m * 3 + 1], cz = cb[m * 3 + 2];
            float sqm = cx * cx + cy * cy + cz * cz;
            float dot = qx * cx + qy * cy + qz * cz;
            float d2 = (sqq + sqm) - 2.0f * dot;
            unsigned u = __float_as_uint(d2);
            u = (u & 0x80000000u) ? ~u : (u | 0x80000000u);
            unsigned long long kk = ((unsigned long long)u << 32) | (unsigned)m;
            key[i] = kk;
            kmin = kk < kmin ? kk : kmin;
        }
        gm[g] = kmin;
    }
    unsigned long long lm = gm[0];
#pragma unroll
    for (int g = 1; g < 8; ++g) lm = gm[g] < lm ? gm[g] : lm;

    for (int sel = 0; sel < 8; ++sel) {
        unsigned long long wmin = lm;
#pragma unroll
        for (int off = 32; off; off >>= 1) {
            unsigned long long o = shfl_xor_u64(wmin, off);
            wmin = o < wmin ? o : wmin;
        }
        if (l == 0) idx_out[(size_t)q * 8 + sel] = (int)(wmin & 0xffffffffu);
        if (lm == wmin) {            // exactly one lane (keys unique)
#pragma unroll
            for (int g = 0; g < 8; ++g) {
                if (gm[g] == wmin) { // 7/8 skipped via execz
                    asm volatile("" ::: "memory");  // forbid if-conversion
                    unsigned long long k0 = key[g * 4 + 0], k1 = key[g * 4 + 1];
                    unsigned long long k2 = key[g * 4 + 2], k3 = key[g * 4 + 3];
                    k0 = (k0 == wmin) ? ~0ULL : k0;
                    k1 = (k1 == wmin) ? ~0ULL : k1;
                    k2 = (k2 == wmin) ? ~0ULL : k2;
                    k3 = (k3 == wmin) ? ~0ULL : k3;
                    key[g * 4 + 0] = k0; key[g * 4 + 1] = k1;
                    key[g * 4 + 2] = k2; key[g * 4 + 3] = k3;
                    unsigned long long a = k0 < k1 ? k0 : k1;
                    unsigned long long c = k2 < k3 ? k2 : k3;
                    gm[g] = a < c ? a : c;
                }
            }
            lm = gm[0];
#pragma unroll
            for (int g = 1; g < 8; ++g) lm = gm[g] < lm ? gm[g] : lm;
        }
    }
}

// ---------------- gather 8 neighbors: sum_k x_no[idx_k][c], std partials ----
__global__ __launch_bounds__(128) void gather_kernel(const float* __restrict__ xn,
                                                     const int* __restrict__ idxb,
                                                     float* __restrict__ sumknn,
                                                     float2* __restrict__ part) {
    int q = blockIdx.x;
    int b = q >> 11;
    int t = threadIdx.x;
    __shared__ int sidx[8];
    if (t < 8) sidx[t] = idxb[(size_t)q * 8 + t];
    __syncthreads();
    const float* xno = xn + ((size_t)b * 2049 + 1) * C384;
    const float* xc  = xn + ((size_t)q + b + 1) * C384;
    float s1 = 0.f, s2 = 0.f;
    for (int c = t; c < C384; c += 128) {
        float xcv = xc[c];
        float acc = 0.f;
#pragma unroll
        for (int k = 0; k < 8; ++k) {
            float v = xno[(size_t)sidx[k] * C384 + c];
            acc += v;
            float d = v - xcv;
            s1 += d;
            s2 += d * d;
        }
        sumknn[(size_t)q * C384 + c] = acc;
    }
    __shared__ float r1[128], r2[128];
    r1[t] = s1; r2[t] = s2;
    __syncthreads();
#pragma unroll
    for (int s = 64; s; s >>= 1) {
        if (t < s) { r1[t] += r1[t + s]; r2[t] += r2[t + s]; }
        __syncthreads();
    }
    if (t == 0) part[q] = make_float2(r1[0], r2[0]);
}

// ---------------- reduce std partials -> inv = 1/(std+1e-5) -----------------
__global__ __launch_bounds__(256) void std_kernel(const float2* __restrict__ part,
                                                  float* __restrict__ stdbuf) {
    int t = threadIdx.x;
    double s1 = 0.0, s2 = 0.0;
    for (int i = t; i < 8192; i += 256) {
        float2 p = part[i];
        s1 += (double)p.x;
        s2 += (double)p.y;
    }
    __shared__ double r1[256], r2[256];
    r1[t] = s1; r2[t] = s2;
    __syncthreads();
#pragma unroll
    for (int s = 128; s; s >>= 1) {
        if (t < s) { r1[t] += r1[t + s]; r2[t] += r2[t + s]; }
        __syncthreads();
    }
    if (t == 0) {
        const double N = 25165824.0;
        double var = (r2[0] - r1[0] * r1[0] / N) / (N - 1.0);
        float stdf = (float)sqrt(var);
        stdbuf[0] = 1.0f / (stdf + 1e-5f);
    }
}

// ---------------- build ef (8192 x 768) bf16 ---------------------------------
__global__ __launch_bounds__(384) void ef_kernel(const float* __restrict__ xn,
                                                 const float* __restrict__ sumknn,
                                                 const float* __restrict__ stdbuf,
                                                 const float* __restrict__ alpha,
                                                 const float* __restrict__ beta,
                                                 unsigned short* __restrict__ ef) {
    int q = blockIdx.x;
    int b = q >> 11;
    int c = threadIdx.x;
    float inv = stdbuf[0];
    float xcv = xn[((size_t)q + b + 1) * C384 + c];
    float mk = sumknn[(size_t)q * C384 + c] * 0.125f;
    float v1 = (mk - xcv) * inv;
    ef[(size_t)q * 768 + c]       = f2bf(alpha[c] * v1 + beta[c]);
    ef[(size_t)q * 768 + 384 + c] = f2bf(alpha[384 + c] * xcv + beta[384 + c]);
}

// ---------------- cls rows ----------------------------------------------------
__global__ void cls_kernel(const float* __restrict__ x,
                           const float* __restrict__ xn,
                           float* __restrict__ out) {
    int b = blockIdx.x;
    int c = threadIdx.x;
    size_t r = (size_t)b * 2049 * C384 + c;
    out[r] = x[r] + xn[r];
}

// ---------------- all 4 weight transposes in one launch ----------------------
__global__ __launch_bounds__(256) void tcast4_kernel(const float* __restrict__ w1,
                                                     const float* __restrict__ w2,
                                                     const float* __restrict__ m1,
                                                     const float* __restrict__ m2,
                                                     unsigned short* __restrict__ o1,
                                                     unsigned short* __restrict__ o2,
                                                     unsigned short* __restrict__ o3,
                                                     unsigned short* __restrict__ o4) {
    int tid = blockIdx.x;
    const float* in; unsigned short* outp; int K, N, local;
    if (tid < 288)       { in = w1; outp = o1; K = 768;  N = 384;  local = tid; }
    else if (tid < 432)  { in = w2; outp = o2; K = 384;  N = 384;  local = tid - 288; }
    else if (tid < 1008) { in = m1; outp = o3; K = 384;  N = 1536; local = tid - 432; }
    else                 { in = m2; outp = o4; K = 1536; N = 384;  local = tid - 1008; }
    int ntN = N >> 5;
    int kb = (local / ntN) * 32, nb = (local % ntN) * 32;
    __shared__ float tile[32][33];
    int c = threadIdx.x & 31, r0 = threadIdx.x >> 5;
#pragma unroll
    for (int i = 0; i < 4; ++i) {
        int r = r0 + i * 8;
        tile[r][c] = in[(size_t)(kb + r) * N + nb + c];
    }
    __syncthreads();
#pragma unroll
    for (int i = 0; i < 4; ++i) {
        int r = r0 + i * 8;
        outp[(size_t)(nb + r) * K + kb + c] = f2bf(tile[c][r]);
    }
}

// ---------------- bf16 MFMA GEMM, 64x64 tile, BK=64, double-buffered ---------
// A: M x K bf16 row-major. Bt: N x K bf16 row-major. out = [res+] act(A@B+bias)
// 2-phase pipeline: issue next tile's global loads BEFORE compute, ds_write
// after; ONE barrier per K-tile. XOR swizzle (row&7)<<4 -> conflict-free.
template <bool GELU, bool REMAP, bool RES, bool OUTBF>
__global__ __launch_bounds__(256) void mfma_gemm(const unsigned short* __restrict__ A,
                                                 const unsigned short* __restrict__ Bt,
                                                 const float* __restrict__ bias,
                                                 const float* __restrict__ res,
                                                 void* __restrict__ outp,
                                                 int M, int N, int K) {
    __shared__ char smem[32768];   // buf0: A[0,8K) B[8K,16K); buf1: +16K
    int t = threadIdx.x;
    int lane = t & 63, w = t >> 6;
    int wr = w >> 1, wc = w & 1;
    int bm = blockIdx.y * 64, bn = blockIdx.x * 64;

    f32x4 acc[2][2] = {};

    int srow = t >> 3;                       // 0..31
    int sc16 = t & 7;                        // 16B chunk in 128B row
    int swz = (sc16 ^ (srow & 7)) << 4;      // same for srow and srow+32

    const unsigned short* pa0 = A + (size_t)(bm + srow) * K + sc16 * 8;
    const unsigned short* pa1 = A + (size_t)(bm + srow + 32) * K + sc16 * 8;
    const unsigned short* pb0 = Bt + (size_t)(bn + srow) * K + sc16 * 8;
    const unsigned short* pb1 = Bt + (size_t)(bn + srow + 32) * K + sc16 * 8;
    bool ok0 = (bm + srow) < M, ok1 = (bm + srow + 32) < M;

    uint4 va0, va1, vb0, vb1;
    const uint4 zz = make_uint4(0u, 0u, 0u, 0u);
    va0 = ok0 ? *(const uint4*)pa0 : zz;
    va1 = ok1 ? *(const uint4*)pa1 : zz;
    vb0 = *(const uint4*)pb0;
    vb1 = *(const uint4*)pb1;
    {
        char* smA = smem;
        char* smB = smem + 8192;
        *(uint4*)(smA + srow * 128 + swz) = va0;
        *(uint4*)(smA + (srow + 32) * 128 + swz) = va1;
        *(uint4*)(smB + srow * 128 + swz) = vb0;
        *(uint4*)(smB + (srow + 32) * 128 + swz) = vb1;
    }

    int nt = K >> 6;
    for (int tix = 0; tix < nt; ++tix) {
        int cur = tix & 1;
        char* smA = smem + cur * 16384;
        char* smB = smA + 8192;
        // issue next tile's global loads early (latency hides under MFMA)
        if (tix + 1 < nt) {
            int ko = (tix + 1) << 6;
            va0 = ok0 ? *(const uint4*)(pa0 + ko) : zz;
            va1 = ok1 ? *(const uint4*)(pa1 + ko) : zz;
            vb0 = *(const uint4*)(pb0 + ko);
            vb1 = *(const uint4*)(pb1 + ko);
        }
        __syncthreads();    // buf[cur] fully written
#pragma unroll
        for (int ks = 0; ks < 2; ++ks) {
            short8 af[2], bfr[2];
            int cb = ks * 4 + (lane >> 4);
#pragma unroll
            for (int mi = 0; mi < 2; ++mi) {
                int row = wr * 32 + mi * 16 + (lane & 15);
                af[mi] = *(const short8*)(smA + row * 128 + ((cb ^ (row & 7)) << 4));
            }
#pragma unroll
            for (int nj = 0; nj < 2; ++nj) {
                int row = wc * 32 + nj * 16 + (lane & 15);
                bfr[nj] = *(const short8*)(smB + row * 128 + ((cb ^ (row & 7)) << 4));
            }
#pragma unroll
            for (int mi = 0; mi < 2; ++mi)
#pragma unroll
                for (int nj = 0; nj < 2; ++nj)
                    acc[mi][nj] = __builtin_amdgcn_mfma_f32_16x16x32_bf16(
                        af[mi], bfr[nj], acc[mi][nj], 0, 0, 0);
        }
        if (tix + 1 < nt) {
            char* dA = smem + (cur ^ 1) * 16384;
            char* dB = dA + 8192;
            *(uint4*)(dA + srow * 128 + swz) = va0;
            *(uint4*)(dA + (srow + 32) * 128 + swz) = va1;
            *(uint4*)(dB + srow * 128 + swz) = vb0;
            *(uint4*)(dB + (srow + 32) * 128 + swz) = vb1;
        }
    }

    // epilogue: C/D layout col=lane&15, row=(lane>>4)*4+reg
#pragma unroll
    for (int nj = 0; nj < 2; ++nj) {
        int n = bn + wc * 32 + nj * 16 + (lane & 15);
        float bs = bias[n];
#pragma unroll
        for (int mi = 0; mi < 2; ++mi) {
#pragma unroll
            for (int r = 0; r < 4; ++r) {
                int m = bm + wr * 32 + mi * 16 + (lane >> 4) * 4 + r;
                if (m >= M) continue;
                float v = acc[mi][nj][r] + bs;
                if (GELU) v = gelu_exact(v);
                size_t orow = REMAP ? (size_t)(m + (m >> 11) + 1) : (size_t)m;
                size_t off = orow * (size_t)N + n;
                if (RES) v += res[off];
                if (OUTBF)
                    ((unsigned short*)outp)[(size_t)m * N + n] = f2bf(v);
                else
                    ((float*)outp)[off] = v;
            }
        }
    }
}

// ---------------------------------------------------------------------------
extern "C" void kernel_launch(void* const* d_in, const int* in_sizes, int n_in,
                              void* d_out, int out_size, void* d_ws, size_t ws_size,
                              hipStream_t stream) {
    const float* center  = (const float*)d_in[0];
    const float* x       = (const float*)d_in[1];
    const float* ln1_g   = (const float*)d_in[2];
    const float* ln1_b   = (const float*)d_in[3];
    const float* alpha   = (const float*)d_in[4];
    const float* beta    = (const float*)d_in[5];
    const float* attn_w1 = (const float*)d_in[6];
    const float* attn_b1 = (const float*)d_in[7];
    const float* attn_w2 = (const float*)d_in[8];
    const float* attn_b2 = (const float*)d_in[9];
    const float* ln2_g   = (const float*)d_in[10];
    const float* ln2_b   = (const float*)d_in[11];
    const float* mlp_w1  = (const float*)d_in[12];
    const float* mlp_b1  = (const float*)d_in[13];
    const float* mlp_w2  = (const float*)d_in[14];
    const float* mlp_b2  = (const float*)d_in[15];
    float* out = (float*)d_out;

    // workspace layout (bytes, all 256-aligned)
    char* wsb = (char*)d_ws;
    float*          xn     = (float*)(wsb + 0);                  // 12,589,056
    float*          sumknn = (float*)(wsb + 12589056);           // 12,582,912
    int*            idxb   = (int*)(wsb + 25171968);             // 262,144
    float2*         part   = (float2*)(wsb + 25434112);          // 65,536
    unsigned short* ef     = (unsigned short*)(wsb + 25499648);  // -> 38,082,560
    unsigned short* g      = (unsigned short*)(wsb + 12589056);  // overlay
    unsigned short* h1     = (unsigned short*)(wsb + 38082560);  // 6,291,456
    unsigned short* yb     = (unsigned short*)(wsb + 44374016);  // 6,294,528
    float*          stdbuf = (float*)(wsb + 50668544);
    unsigned short* w1T    = (unsigned short*)(wsb + 50668800);
    unsigned short* w2T    = (unsigned short*)(wsb + 51258624);
    unsigned short* mw1T   = (unsigned short*)(wsb + 51553536);
    unsigned short* mw2T   = (unsigned short*)(wsb + 52733184);

    tcast4_kernel<<<1584, 256, 0, stream>>>(attn_w1, attn_w2, mlp_w1, mlp_w2,
                                            w1T, w2T, mw1T, mw2T);
    ln_kernel<false><<<8196, 128, 0, stream>>>(x, xn, ln1_g, ln1_b);
    knn_kernel<<<2048, 256, 0, stream>>>(center, idxb);
    gather_kernel<<<8192, 128, 0, stream>>>(xn, idxb, sumknn, part);
    std_kernel<<<1, 256, 0, stream>>>(part, stdbuf);
    ef_kernel<<<8192, 384, 0, stream>>>(xn, sumknn, stdbuf, alpha, beta, ef);
    mfma_gemm<true, false, false, true><<<dim3(6, 128), 256, 0, stream>>>(
        ef, w1T, attn_b1, nullptr, h1, 8192, 384, 768);
    mfma_gemm<false, true, true, false><<<dim3(6, 128), 256, 0, stream>>>(
        h1, w2T, attn_b2, x, out, 8192, 384, 384);
    cls_kernel<<<4, 384, 0, stream>>>(x, xn, out);
    ln_kernel<true><<<8196, 128, 0, stream>>>(out, yb, ln2_g, ln2_b);
    mfma_gemm<true, false, false, true><<<dim3(24, 129), 256, 0, stream>>>(
        yb, mw1T, mlp_b1, nullptr, g, 8196, 1536, 384);
    mfma_gemm<false, false, true, false><<<dim3(6, 129), 256, 0, stream>>>(
        g, mw2T, mlp_b2, out, out, 8196, 384, 1536);
}